// Round 4
// baseline (567.499 us; speedup 1.0000x reference)
//
#include <hip/hip_runtime.h>
#include <hip/hip_bf16.h>
#include <stdint.h>

#define FDIM   1024
#define NCLS   100
#define CDIM   512
#define NBATCH 4096

typedef __attribute__((ext_vector_type(8))) short short8;
typedef __attribute__((ext_vector_type(4))) float f32x4;

typedef const __attribute__((address_space(1))) unsigned int guint;
typedef __attribute__((address_space(3))) unsigned int luint;

__device__ __forceinline__ void gl_lds16(const unsigned short* g, unsigned short* l) {
    __builtin_amdgcn_global_load_lds((guint*)g, (luint*)l, 16, 0, 0);
}

__device__ __forceinline__ unsigned short f2bf_bits(float f) {
    union { float f; uint32_t u; } v; v.f = f;
    uint32_t u = v.u;
    return (unsigned short)((u + 0x7FFFu + ((u >> 16) & 1u)) >> 16);
}

// ---- convert x: f32 [4096][1024] -> bf16 same layout ----
__global__ void cvt_x_kernel(const float* __restrict__ x, unsigned short* __restrict__ xb) {
    const int i = (blockIdx.x * 256 + threadIdx.x) * 8;
    f32x4 a = *(const f32x4*)(x + i);
    f32x4 b = *(const f32x4*)(x + i + 4);
    short8 h;
#pragma unroll
    for (int e = 0; e < 4; ++e) { h[e] = (short)f2bf_bits(a[e]); h[e + 4] = (short)f2bf_bits(b[e]); }
    *(short8*)(xb + i) = h;
}

// ---- convert weight: f32 [m][n][j] -> bf16 [n][m][j] ----
__global__ void cvt_w_kernel(const float* __restrict__ w, unsigned short* __restrict__ wb) {
    const int mn = blockIdx.x;              // m*NCLS + n
    const int m = mn / NCLS, n = mn % NCLS;
    const float* src = w + (size_t)mn * FDIM;
    unsigned short* dst = wb + ((size_t)n * CDIM + m) * FDIM;
    const int c = threadIdx.x * 8;
    f32x4 a = *(const f32x4*)(src + c);
    f32x4 b = *(const f32x4*)(src + c + 4);
    short8 h;
#pragma unroll
    for (int e = 0; e < 4; ++e) { h[e] = (short)f2bf_bits(a[e]); h[e + 4] = (short)f2bf_bits(b[e]); }
    *(short8*)(dst + c) = h;
}

// ---- fused DUQ, 256x256x64, T3+T4: raw barriers + counted vmcnt(8) ----
// Per K-tile it: {stage it+1 (8 gl_lds, older-first discipline), vmcnt(8)
// [== tile it's 8 oldest retired, it+1's stay in flight], B1, 4 quadrant
// phases with reg-pipelined ds_reads + setprio'd MFMA clusters, B2}.
// Only vmem ops inside the loop are the 8 gl_lds -> vmcnt counting is exact.
__global__ __launch_bounds__(512, 2)
void duq8(const unsigned short* __restrict__ xb, const unsigned short* __restrict__ wb,
          const float* __restrict__ csum, const float* __restrict__ cnum,
          float* __restrict__ out) {
    __shared__ unsigned short lsA[2][256 * 64];   // 2 x 32 KB
    __shared__ unsigned short lsB[2][256 * 64];   // 2 x 32 KB
    __shared__ float c_lds[CDIM];
    __shared__ float red[4][256];

    const int t    = threadIdx.x;
    const int bid  = blockIdx.x;
    const int n    = bid >> 4;       // class 0..99
    const int rt   = bid & 15;       // 256-row batch tile
    const int lane = t & 63;
    const int wid  = t >> 6;         // 0..7
    const int wm   = wid >> 2;       // 0..1 : rows wm*128..+127
    const int wn   = wid & 3;        // 0..3 : cols wn*64..+63
    const int ln15 = lane & 15;
    const int hi   = lane >> 4;

    {
        const float inv = 1.0f / cnum[n];
        for (int m = t; m < CDIM; m += 512)
            c_lds[m] = csum[(size_t)m * NCLS + n] * inv;
    }
    __syncthreads();   // c_lds visible; full drain OK here (nothing in flight)

    // pre-swizzled staging source (verified r1-r3: 0 bank conflicts, correct)
    const int st_r = t >> 3;                       // 0..63
    const int st_c = ((t & 7) ^ (st_r & 7)) * 8;
    const unsigned short* gA = xb + ((size_t)(rt * 256 + st_r)) * FDIM + st_c;
    const unsigned short* gB = wb + ((size_t)n * CDIM + st_r) * FDIM + st_c;

    auto stage = [&](int it_, int bsel_) {
        const int k_  = (it_ & 15) * 64;
        const int pn_ = it_ >> 4;
#pragma unroll
        for (int c = 0; c < 4; ++c) {
            gl_lds16(gA + (size_t)(c * 64) * FDIM + k_,
                     &lsA[bsel_][c * 4096 + wid * 512]);
            gl_lds16(gB + ((size_t)(pn_ * 256 + c * 64)) * FDIM + k_,
                     &lsB[bsel_][c * 4096 + wid * 512]);
        }
    };

    f32x4 acc[8][4];
#pragma unroll
    for (int i = 0; i < 8; ++i)
#pragma unroll
        for (int j = 0; j < 4; ++j) acc[i][j] = f32x4{0.0f, 0.0f, 0.0f, 0.0f};

    stage(0, 0);

    for (int it = 0; it < 32; ++it) {
        const int bs = it & 1;

        __builtin_amdgcn_sched_barrier(0);
        if (it + 1 < 32) {
            stage(it + 1, bs ^ 1);   // writes buf[bs^1]; its readers passed B2 of it-1
            __builtin_amdgcn_sched_barrier(0);
            asm volatile("s_waitcnt vmcnt(8)" ::: "memory");  // tile it done; it+1 in flight
        } else {
            asm volatile("s_waitcnt vmcnt(0)" ::: "memory");  // last tile: full drain
        }
        __builtin_amdgcn_sched_barrier(0);
        __builtin_amdgcn_s_barrier();                          // B1: tile it ready for ALL waves
        __builtin_amdgcn_sched_barrier(0);

        const char* lA = (const char*)lsA[bs];
        const char* lB = (const char*)lsB[bs];

        short8 a0[4][2], a1[4][2], b0[2][2], b1[2][2];
        // p0 fragments
#pragma unroll
        for (int i = 0; i < 4; ++i) {
            const int row = wm * 128 + i * 16 + ln15;
#pragma unroll
            for (int kk = 0; kk < 2; ++kk) {
                const int ba = (row * 128 + (kk * 32 + hi * 8) * 2) ^ ((row & 7) << 4);
                a0[i][kk] = *(const short8*)(lA + ba);
            }
        }
#pragma unroll
        for (int j = 0; j < 2; ++j) {
            const int row = wn * 64 + j * 16 + ln15;
#pragma unroll
            for (int kk = 0; kk < 2; ++kk) {
                const int bb = (row * 128 + (kk * 32 + hi * 8) * 2) ^ ((row & 7) << 4);
                b0[j][kk] = *(const short8*)(lB + bb);
            }
        }
        // p1 fragments issued before p0 compute (compiler emits counted lgkmcnt)
#pragma unroll
        for (int j = 0; j < 2; ++j) {
            const int row = wn * 64 + (2 + j) * 16 + ln15;
#pragma unroll
            for (int kk = 0; kk < 2; ++kk) {
                const int bb = (row * 128 + (kk * 32 + hi * 8) * 2) ^ ((row & 7) << 4);
                b1[j][kk] = *(const short8*)(lB + bb);
            }
        }
        __builtin_amdgcn_s_setprio(1);
#pragma unroll
        for (int i = 0; i < 4; ++i)
#pragma unroll
            for (int j = 0; j < 2; ++j)
#pragma unroll
                for (int kk = 0; kk < 2; ++kk)
                    acc[i][j] = __builtin_amdgcn_mfma_f32_16x16x32_bf16(
                        a0[i][kk], b0[j][kk], acc[i][j], 0, 0, 0);
        __builtin_amdgcn_s_setprio(0);
        // p2 fragments issued before p1 compute
#pragma unroll
        for (int i = 0; i < 4; ++i) {
            const int row = wm * 128 + (4 + i) * 16 + ln15;
#pragma unroll
            for (int kk = 0; kk < 2; ++kk) {
                const int ba = (row * 128 + (kk * 32 + hi * 8) * 2) ^ ((row & 7) << 4);
                a1[i][kk] = *(const short8*)(lA + ba);
            }
        }
        __builtin_amdgcn_s_setprio(1);
#pragma unroll
        for (int i = 0; i < 4; ++i)
#pragma unroll
            for (int j = 0; j < 2; ++j)
#pragma unroll
                for (int kk = 0; kk < 2; ++kk)
                    acc[i][2 + j] = __builtin_amdgcn_mfma_f32_16x16x32_bf16(
                        a0[i][kk], b1[j][kk], acc[i][2 + j], 0, 0, 0);
        __builtin_amdgcn_s_setprio(0);
        __builtin_amdgcn_s_setprio(1);
#pragma unroll
        for (int i = 0; i < 4; ++i)
#pragma unroll
            for (int j = 0; j < 2; ++j)
#pragma unroll
                for (int kk = 0; kk < 2; ++kk)
                    acc[4 + i][j] = __builtin_amdgcn_mfma_f32_16x16x32_bf16(
                        a1[i][kk], b0[j][kk], acc[4 + i][j], 0, 0, 0);
#pragma unroll
        for (int i = 0; i < 4; ++i)
#pragma unroll
            for (int j = 0; j < 2; ++j)
#pragma unroll
                for (int kk = 0; kk < 2; ++kk)
                    acc[4 + i][2 + j] = __builtin_amdgcn_mfma_f32_16x16x32_bf16(
                        a1[i][kk], b1[j][kk], acc[4 + i][2 + j], 0, 0, 0);
        __builtin_amdgcn_s_setprio(0);

        if ((it & 15) == 15) {       // panel epilogue: fold (z-c)^2
            const int pn = it >> 4;
            float p[8][4];
#pragma unroll
            for (int i = 0; i < 8; ++i)
#pragma unroll
                for (int r = 0; r < 4; ++r) p[i][r] = 0.0f;
#pragma unroll
            for (int i = 0; i < 8; ++i)
#pragma unroll
                for (int j = 0; j < 4; ++j) {
                    const int m = pn * 256 + wn * 64 + j * 16 + ln15;
                    const float c = c_lds[m];
#pragma unroll
                    for (int r = 0; r < 4; ++r) {
                        const float d = acc[i][j][r] - c;
                        p[i][r] += d * d;
                        acc[i][j][r] = 0.0f;
                    }
                }
#pragma unroll
            for (int i = 0; i < 8; ++i)
#pragma unroll
                for (int r = 0; r < 4; ++r) {
                    float v = p[i][r];
                    v += __shfl_xor(v, 1);
                    v += __shfl_xor(v, 2);
                    v += __shfl_xor(v, 4);
                    v += __shfl_xor(v, 8);
                    p[i][r] = v;
                }
            if (ln15 == 0) {
#pragma unroll
                for (int i = 0; i < 8; ++i)
#pragma unroll
                    for (int r = 0; r < 4; ++r) {
                        const int row = wm * 128 + i * 16 + hi * 4 + r;
                        if (pn == 0) red[wn][row] = p[i][r];
                        else         red[wn][row] += p[i][r];
                    }
            }
        }

        __builtin_amdgcn_sched_barrier(0);
        __builtin_amdgcn_s_barrier();                          // B2: reads of buf[bs] done
        __builtin_amdgcn_sched_barrier(0);
    }

    __syncthreads();
    if (t < 256) {
        const float sq = (red[0][t] + red[1][t] + red[2][t] + red[3][t]) * (1.0f / 512.0f);
        const float lc = -50.0f * sq;                    // -sq / (2*0.1^2)
        const size_t b = (size_t)rt * 256 + t;
        out[b * NCLS + n] = expf(lc);
        out[(size_t)NBATCH * NCLS + b * NCLS + n] = lc;
    }
}

// ---- fallback (no workspace): reg-staged inline-convert variant (r1, verified) ----
__global__ __launch_bounds__(256, 2)
void duq_fallback(const float* __restrict__ x, const float* __restrict__ w,
                  const float* __restrict__ csum, const float* __restrict__ cnum,
                  float* __restrict__ out) {
    __shared__ unsigned short lsA[128 * 64];
    __shared__ unsigned short lsB[128 * 64];
    __shared__ float c_lds[CDIM];
    __shared__ float red[2][128];

    const int t = threadIdx.x;
    const int n    = blockIdx.x >> 5;
    const int tile = blockIdx.x & 31;
    const int lane = t & 63;
    const int wid  = t >> 6;
    const int wrow = wid >> 1;
    const int wcol = wid & 1;
    const int ln15 = lane & 15;
    const int hi   = lane >> 4;

    {
        const float inv = 1.0f / cnum[n];
        for (int m = t; m < CDIM; m += 256)
            c_lds[m] = csum[(size_t)m * NCLS + n] * inv;
    }

    const int srow = t >> 3;
    const int scol = (t & 7) * 8;
    const int swz  = (srow & 7) << 4;

    float p[16];
#pragma unroll
    for (int q = 0; q < 16; ++q) p[q] = 0.0f;

    for (int chunk = 0; chunk < 4; ++chunk) {
        f32x4 acc[4][4];
#pragma unroll
        for (int i = 0; i < 4; ++i)
#pragma unroll
            for (int j = 0; j < 4; ++j)
                acc[i][j] = f32x4{0.0f, 0.0f, 0.0f, 0.0f};

        for (int ks = 0; ks < 16; ++ks) {
            const int k = ks * 64;
            __syncthreads();
#pragma unroll
            for (int pp = 0; pp < 4; ++pp) {
                const int row = pp * 32 + srow;
                const float* pa = x + ((size_t)(tile * 128 + row)) * FDIM + k + scol;
                const float* pb = w + ((size_t)(chunk * 128 + row) * NCLS + n) * FDIM + k + scol;
                f32x4 a0 = *(const f32x4*)pa, a1 = *(const f32x4*)(pa + 4);
                f32x4 b0 = *(const f32x4*)pb, b1 = *(const f32x4*)(pb + 4);
                short8 ha, hb;
#pragma unroll
                for (int e = 0; e < 4; ++e) {
                    ha[e] = (short)f2bf_bits(a0[e]); ha[e + 4] = (short)f2bf_bits(a1[e]);
                    hb[e] = (short)f2bf_bits(b0[e]); hb[e + 4] = (short)f2bf_bits(b1[e]);
                }
                const int byte = (row * 128 + scol * 2) ^ swz;
                *(short8*)((char*)lsA + byte) = ha;
                *(short8*)((char*)lsB + byte) = hb;
            }
            __syncthreads();
#pragma unroll
            for (int kk = 0; kk < 2; ++kk) {
                short8 af[4], bfr[4];
#pragma unroll
                for (int i = 0; i < 4; ++i) {
                    const int rowA = wrow * 64 + i * 16 + ln15;
                    const int ba = (rowA * 128 + (kk * 32 + hi * 8) * 2) ^ ((rowA & 7) << 4);
                    af[i] = *(const short8*)((const char*)lsA + ba);
                    const int rowB = wcol * 64 + i * 16 + ln15;
                    const int bb = (rowB * 128 + (kk * 32 + hi * 8) * 2) ^ ((rowB & 7) << 4);
                    bfr[i] = *(const short8*)((const char*)lsB + bb);
                }
#pragma unroll
                for (int i = 0; i < 4; ++i)
#pragma unroll
                    for (int j = 0; j < 4; ++j)
                        acc[i][j] = __builtin_amdgcn_mfma_f32_16x16x32_bf16(af[i], bfr[j], acc[i][j], 0, 0, 0);
            }
        }

#pragma unroll
        for (int i = 0; i < 4; ++i)
#pragma unroll
            for (int j = 0; j < 4; ++j) {
                const int m = chunk * 128 + wcol * 64 + j * 16 + ln15;
                const float c = c_lds[m];
#pragma unroll
                for (int r = 0; r < 4; ++r) {
                    const float d = acc[i][j][r] - c;
                    p[i * 4 + r] += d * d;
                }
            }
    }

#pragma unroll
    for (int q = 0; q < 16; ++q) {
        float v = p[q];
        v += __shfl_xor(v, 1);
        v += __shfl_xor(v, 2);
        v += __shfl_xor(v, 4);
        v += __shfl_xor(v, 8);
        p[q] = v;
    }
    __syncthreads();
    if (ln15 == 0) {
#pragma unroll
        for (int i = 0; i < 4; ++i)
#pragma unroll
            for (int r = 0; r < 4; ++r)
                red[wcol][wrow * 64 + i * 16 + hi * 4 + r] = p[i * 4 + r];
    }
    __syncthreads();
    if (t < 128) {
        const float sq = (red[0][t] + red[1][t]) * (1.0f / 512.0f);
        const float lc = -50.0f * sq;
        const size_t b = (size_t)tile * 128 + t;
        out[b * NCLS + n] = expf(lc);
        out[(size_t)NBATCH * NCLS + b * NCLS + n] = lc;
    }
}

extern "C" void kernel_launch(void* const* d_in, const int* in_sizes, int n_in,
                              void* d_out, int out_size, void* d_ws, size_t ws_size,
                              hipStream_t stream) {
    const float* x    = (const float*)d_in[0];
    const float* w    = (const float*)d_in[1];
    const float* csum = (const float*)d_in[2];
    const float* cnum = (const float*)d_in[3];
    float* out = (float*)d_out;

    const size_t need = ((size_t)NBATCH * FDIM + (size_t)CDIM * NCLS * FDIM) * sizeof(unsigned short);

    if (ws_size >= need) {
        unsigned short* xb = (unsigned short*)d_ws;
        unsigned short* wb = xb + (size_t)NBATCH * FDIM;
        cvt_x_kernel<<<dim3((NBATCH * FDIM) / 2048), dim3(256), 0, stream>>>(x, xb);
        cvt_w_kernel<<<dim3(CDIM * NCLS), dim3(128), 0, stream>>>(w, wb);
        duq8<<<dim3(NCLS * 16), dim3(512), 0, stream>>>(xb, wb, csum, cnum, out);
    } else {
        duq_fallback<<<dim3(NCLS * 32), dim3(256), 0, stream>>>(x, w, csum, cnum, out);
    }
}

// Round 5
// 536.764 us; speedup vs baseline: 1.0573x; 1.0573x over previous
//
#include <hip/hip_runtime.h>
#include <hip/hip_bf16.h>
#include <stdint.h>

#define FDIM   1024
#define NCLS   100
#define CDIM   512
#define NBATCH 4096

typedef __attribute__((ext_vector_type(8))) short short8;
typedef __attribute__((ext_vector_type(4))) float f32x4;

typedef const __attribute__((address_space(1))) unsigned int guint;
typedef __attribute__((address_space(3))) unsigned int luint;

__device__ __forceinline__ void gl_lds16(const unsigned short* g, unsigned short* l) {
    __builtin_amdgcn_global_load_lds((guint*)g, (luint*)l, 16, 0, 0);
}

__device__ __forceinline__ unsigned short f2bf_bits(float f) {
    union { float f; uint32_t u; } v; v.f = f;
    uint32_t u = v.u;
    return (unsigned short)((u + 0x7FFFu + ((u >> 16) & 1u)) >> 16);
}

// ---- convert x: f32 [4096][1024] -> bf16 same layout ----
__global__ void cvt_x_kernel(const float* __restrict__ x, unsigned short* __restrict__ xb) {
    const int i = (blockIdx.x * 256 + threadIdx.x) * 8;
    f32x4 a = *(const f32x4*)(x + i);
    f32x4 b = *(const f32x4*)(x + i + 4);
    short8 h;
#pragma unroll
    for (int e = 0; e < 4; ++e) { h[e] = (short)f2bf_bits(a[e]); h[e + 4] = (short)f2bf_bits(b[e]); }
    *(short8*)(xb + i) = h;
}

// ---- convert weight: f32 [m][n][j] -> bf16 [n][m][j] ----
__global__ void cvt_w_kernel(const float* __restrict__ w, unsigned short* __restrict__ wb) {
    const int mn = blockIdx.x;              // m*NCLS + n
    const int m = mn / NCLS, n = mn % NCLS;
    const float* src = w + (size_t)mn * FDIM;
    unsigned short* dst = wb + ((size_t)n * CDIM + m) * FDIM;
    const int c = threadIdx.x * 8;
    f32x4 a = *(const f32x4*)(src + c);
    f32x4 b = *(const f32x4*)(src + c + 4);
    short8 h;
#pragma unroll
    for (int e = 0; e < 4; ++e) { h[e] = (short)f2bf_bits(a[e]); h[e + 4] = (short)f2bf_bits(b[e]); }
    *(short8*)(dst + c) = h;
}

// ---- fused DUQ, 256x256x64, m201-style 4-phase schedule ----
// Per K-tile t (reading buf bs, staging tile t+1 into buf bs^1, 2 gl_lds/phase):
//   P0: read a[qr0](8) b[qc0](4) | stage c0,c1 | bar | lgkm0 | 16 MFMA | bar
//   P1: read b[qc1](4)           | stage c2,c3 | bar | lgkm0 | 16 MFMA | vmcnt(4) bar
//   P2: read a[qr1](8)           | stage c4,c5 | bar | lgkm0 | 16 MFMA | bar
//   P3: (regs)                   | stage c6,c7 | bar |         16 MFMA | vmcnt(2) bar
// Chunk order c0..c7 = A[0:64],A[128:192],B[0:64],B[64:128],B[128:192],B[192:256],
// A[64:128],A[192:256]: P0 needs c0..c5 (vmcnt(2) left c6,c7 of NEXT tile in
// flight), P2 needs c6,c7 (vmcnt(4) retired them). Never drains to 0 mid-loop.
__global__ __launch_bounds__(512, 2)
void duq8(const unsigned short* __restrict__ xb, const unsigned short* __restrict__ wb,
          const float* __restrict__ csum, const float* __restrict__ cnum,
          float* __restrict__ out) {
    __shared__ unsigned short lsA[2][256 * 64];   // 2 x 32 KB
    __shared__ unsigned short lsB[2][256 * 64];   // 2 x 32 KB
    __shared__ float c_lds[CDIM];
    __shared__ float red[4][256];

    const int t    = threadIdx.x;
    const int bid  = blockIdx.x;
    const int n    = bid >> 4;       // class 0..99
    const int rt   = bid & 15;       // 256-row batch tile
    const int lane = t & 63;
    const int wm   = (t >> 6) >> 2;  // 0..1 : rows wm*128..+127
    const int wn   = (t >> 6) & 3;   // 0..3 : cols wn*64..+63
    const int ln15 = lane & 15;
    const int hi   = lane >> 4;

    {
        const float inv = 1.0f / cnum[n];
        for (int m = t; m < CDIM; m += 512)
            c_lds[m] = csum[(size_t)m * NCLS + n] * inv;
    }
    __syncthreads();

    // staging: thread covers row chunkbase+(t>>3), 16B at pre-swizzled col
    const int st_r = t >> 3;                       // 0..63
    const int st_c = ((t & 7) ^ (st_r & 7)) * 8;
    const unsigned short* gA = xb + ((size_t)(rt * 256 + st_r)) * FDIM + st_c;
    const unsigned short* gBb = wb + ((size_t)n * CDIM + st_r) * FDIM + st_c;
    const int ldst = st_r * 64 + (t & 7) * 8;      // linear dest (elements)

    // chunk row offsets: A chunks c0,c1,c6,c7 -> 0,128,64,192 ; B c2..c5 -> 0,64,128,192
    auto stageA = [&](int rowoff, int tt, int bsel) {
        const int k_ = (tt & 15) * 64;
        gl_lds16(gA + (size_t)rowoff * FDIM + k_, &lsA[bsel][rowoff * 64 + ldst]);
    };
    auto stageB = [&](int rowoff, int tt, int bsel) {
        const int k_ = (tt & 15) * 64;
        const int pn_ = tt >> 4;
        gl_lds16(gBb + (size_t)(pn_ * 256 + rowoff) * FDIM + k_, &lsB[bsel][rowoff * 64 + ldst]);
    };

    f32x4 acc[8][4];
#pragma unroll
    for (int i = 0; i < 8; ++i)
#pragma unroll
        for (int j = 0; j < 4; ++j) acc[i][j] = f32x4{0.0f, 0.0f, 0.0f, 0.0f};

    // prologue: stage tile 0 in chunk order; leave c6,c7 in flight
    stageA(0, 0, 0); stageA(128, 0, 0);
    stageB(0, 0, 0); stageB(64, 0, 0); stageB(128, 0, 0); stageB(192, 0, 0);
    stageA(64, 0, 0); stageA(192, 0, 0);
    asm volatile("s_waitcnt vmcnt(2)");
    __builtin_amdgcn_s_barrier();

    short8 af[4][2], bf[2][2][2];

    for (int it = 0; it < 32; ++it) {
        const int bs = it & 1;
        const bool more = (it + 1 < 32);
        const char* lA = (const char*)lsA[bs];
        const char* lB = (const char*)lsB[bs];

        // ---------------- P0 : quadrant (qr0,qc0) ----------------
#pragma unroll
        for (int i = 0; i < 4; ++i) {
            const int row = wm * 128 + i * 16 + ln15;
#pragma unroll
            for (int kk = 0; kk < 2; ++kk) {
                const int ba = (row * 128 + (kk * 32 + hi * 8) * 2) ^ ((row & 7) << 4);
                af[i][kk] = *(const short8*)(lA + ba);
            }
        }
#pragma unroll
        for (int j = 0; j < 2; ++j) {
            const int row = wn * 64 + j * 16 + ln15;
#pragma unroll
            for (int kk = 0; kk < 2; ++kk) {
                const int bb = (row * 128 + (kk * 32 + hi * 8) * 2) ^ ((row & 7) << 4);
                bf[0][j][kk] = *(const short8*)(lB + bb);
            }
        }
        if (more) { stageA(0, it + 1, bs ^ 1); stageA(128, it + 1, bs ^ 1); }
        __builtin_amdgcn_s_barrier();
        asm volatile("s_waitcnt lgkmcnt(0)");
        __builtin_amdgcn_sched_barrier(0);
        __builtin_amdgcn_s_setprio(1);
#pragma unroll
        for (int i = 0; i < 4; ++i)
#pragma unroll
            for (int j = 0; j < 2; ++j)
#pragma unroll
                for (int kk = 0; kk < 2; ++kk)
                    acc[i][j] = __builtin_amdgcn_mfma_f32_16x16x32_bf16(
                        af[i][kk], bf[0][j][kk], acc[i][j], 0, 0, 0);
        __builtin_amdgcn_s_setprio(0);
        __builtin_amdgcn_s_barrier();

        // ---------------- P1 : quadrant (qr0,qc1) ----------------
#pragma unroll
        for (int j = 0; j < 2; ++j) {
            const int row = wn * 64 + (2 + j) * 16 + ln15;
#pragma unroll
            for (int kk = 0; kk < 2; ++kk) {
                const int bb = (row * 128 + (kk * 32 + hi * 8) * 2) ^ ((row & 7) << 4);
                bf[1][j][kk] = *(const short8*)(lB + bb);
            }
        }
        if (more) { stageB(0, it + 1, bs ^ 1); stageB(64, it + 1, bs ^ 1); }
        __builtin_amdgcn_s_barrier();
        asm volatile("s_waitcnt lgkmcnt(0)");
        __builtin_amdgcn_sched_barrier(0);
        __builtin_amdgcn_s_setprio(1);
#pragma unroll
        for (int i = 0; i < 4; ++i)
#pragma unroll
            for (int j = 0; j < 2; ++j)
#pragma unroll
                for (int kk = 0; kk < 2; ++kk)
                    acc[i][2 + j] = __builtin_amdgcn_mfma_f32_16x16x32_bf16(
                        af[i][kk], bf[1][j][kk], acc[i][2 + j], 0, 0, 0);
        __builtin_amdgcn_s_setprio(0);
        if (more) asm volatile("s_waitcnt vmcnt(4)");   // retire c6,c7(it) for P2
        else      asm volatile("s_waitcnt vmcnt(0)");
        __builtin_amdgcn_s_barrier();

        // ---------------- P2 : quadrant (qr1,qc0) ----------------
#pragma unroll
        for (int i = 0; i < 4; ++i) {
            const int row = wm * 128 + 64 + i * 16 + ln15;
#pragma unroll
            for (int kk = 0; kk < 2; ++kk) {
                const int ba = (row * 128 + (kk * 32 + hi * 8) * 2) ^ ((row & 7) << 4);
                af[i][kk] = *(const short8*)(lA + ba);
            }
        }
        if (more) { stageB(128, it + 1, bs ^ 1); stageB(192, it + 1, bs ^ 1); }
        __builtin_amdgcn_s_barrier();
        asm volatile("s_waitcnt lgkmcnt(0)");
        __builtin_amdgcn_sched_barrier(0);
        __builtin_amdgcn_s_setprio(1);
#pragma unroll
        for (int i = 0; i < 4; ++i)
#pragma unroll
            for (int j = 0; j < 2; ++j)
#pragma unroll
                for (int kk = 0; kk < 2; ++kk)
                    acc[4 + i][j] = __builtin_amdgcn_mfma_f32_16x16x32_bf16(
                        af[i][kk], bf[0][j][kk], acc[4 + i][j], 0, 0, 0);
        __builtin_amdgcn_s_setprio(0);
        __builtin_amdgcn_s_barrier();

        // ---------------- P3 : quadrant (qr1,qc1) ----------------
        if (more) { stageA(64, it + 1, bs ^ 1); stageA(192, it + 1, bs ^ 1); }
        __builtin_amdgcn_s_barrier();
        __builtin_amdgcn_s_setprio(1);
#pragma unroll
        for (int i = 0; i < 4; ++i)
#pragma unroll
            for (int j = 0; j < 2; ++j)
#pragma unroll
                for (int kk = 0; kk < 2; ++kk)
                    acc[4 + i][2 + j] = __builtin_amdgcn_mfma_f32_16x16x32_bf16(
                        af[i][kk], bf[1][j][kk], acc[4 + i][2 + j], 0, 0, 0);
        __builtin_amdgcn_s_setprio(0);

        if ((it & 15) == 15) {       // panel epilogue: fold (z-c)^2 (regs + red[])
            const int pn = it >> 4;
            float p[8][4];
#pragma unroll
            for (int i = 0; i < 8; ++i)
#pragma unroll
                for (int r = 0; r < 4; ++r) p[i][r] = 0.0f;
#pragma unroll
            for (int i = 0; i < 8; ++i)
#pragma unroll
                for (int j = 0; j < 4; ++j) {
                    const int m = pn * 256 + wn * 64 + j * 16 + ln15;
                    const float c = c_lds[m];
#pragma unroll
                    for (int r = 0; r < 4; ++r) {
                        const float d = acc[i][j][r] - c;
                        p[i][r] += d * d;
                        acc[i][j][r] = 0.0f;
                    }
                }
#pragma unroll
            for (int i = 0; i < 8; ++i)
#pragma unroll
                for (int r = 0; r < 4; ++r) {
                    float v = p[i][r];
                    v += __shfl_xor(v, 1);
                    v += __shfl_xor(v, 2);
                    v += __shfl_xor(v, 4);
                    v += __shfl_xor(v, 8);
                    p[i][r] = v;
                }
            if (ln15 == 0) {
#pragma unroll
                for (int i = 0; i < 8; ++i)
#pragma unroll
                    for (int r = 0; r < 4; ++r) {
                        const int row = wm * 128 + i * 16 + hi * 4 + r;
                        if (pn == 0) red[wn][row] = p[i][r];
                        else         red[wn][row] += p[i][r];
                    }
            }
        }

        if (more) asm volatile("s_waitcnt vmcnt(2)");   // retire c0..c5(it+1) for next P0
        __builtin_amdgcn_s_barrier();
    }

    __syncthreads();
    if (t < 256) {
        const float sq = (red[0][t] + red[1][t] + red[2][t] + red[3][t]) * (1.0f / 512.0f);
        const float lc = -50.0f * sq;                    // -sq / (2*0.1^2)
        const size_t b = (size_t)rt * 256 + t;
        out[b * NCLS + n] = expf(lc);
        out[(size_t)NBATCH * NCLS + b * NCLS + n] = lc;
    }
}

// ---- fallback (no workspace): reg-staged inline-convert variant (r1, verified) ----
__global__ __launch_bounds__(256, 2)
void duq_fallback(const float* __restrict__ x, const float* __restrict__ w,
                  const float* __restrict__ csum, const float* __restrict__ cnum,
                  float* __restrict__ out) {
    __shared__ unsigned short lsA[128 * 64];
    __shared__ unsigned short lsB[128 * 64];
    __shared__ float c_lds[CDIM];
    __shared__ float red[2][128];

    const int t = threadIdx.x;
    const int n    = blockIdx.x >> 5;
    const int tile = blockIdx.x & 31;
    const int lane = t & 63;
    const int wid  = t >> 6;
    const int wrow = wid >> 1;
    const int wcol = wid & 1;
    const int ln15 = lane & 15;
    const int hi   = lane >> 4;

    {
        const float inv = 1.0f / cnum[n];
        for (int m = t; m < CDIM; m += 256)
            c_lds[m] = csum[(size_t)m * NCLS + n] * inv;
    }

    const int srow = t >> 3;
    const int scol = (t & 7) * 8;
    const int swz  = (srow & 7) << 4;

    float p[16];
#pragma unroll
    for (int q = 0; q < 16; ++q) p[q] = 0.0f;

    for (int chunk = 0; chunk < 4; ++chunk) {
        f32x4 acc[4][4];
#pragma unroll
        for (int i = 0; i < 4; ++i)
#pragma unroll
            for (int j = 0; j < 4; ++j)
                acc[i][j] = f32x4{0.0f, 0.0f, 0.0f, 0.0f};

        for (int ks = 0; ks < 16; ++ks) {
            const int k = ks * 64;
            __syncthreads();
#pragma unroll
            for (int pp = 0; pp < 4; ++pp) {
                const int row = pp * 32 + srow;
                const float* pa = x + ((size_t)(tile * 128 + row)) * FDIM + k + scol;
                const float* pb = w + ((size_t)(chunk * 128 + row) * NCLS + n) * FDIM + k + scol;
                f32x4 a0 = *(const f32x4*)pa, a1 = *(const f32x4*)(pa + 4);
                f32x4 b0 = *(const f32x4*)pb, b1 = *(const f32x4*)(pb + 4);
                short8 ha, hb;
#pragma unroll
                for (int e = 0; e < 4; ++e) {
                    ha[e] = (short)f2bf_bits(a0[e]); ha[e + 4] = (short)f2bf_bits(a1[e]);
                    hb[e] = (short)f2bf_bits(b0[e]); hb[e + 4] = (short)f2bf_bits(b1[e]);
                }
                const int byte = (row * 128 + scol * 2) ^ swz;
                *(short8*)((char*)lsA + byte) = ha;
                *(short8*)((char*)lsB + byte) = hb;
            }
            __syncthreads();
#pragma unroll
            for (int kk = 0; kk < 2; ++kk) {
                short8 afr[4], bfr[4];
#pragma unroll
                for (int i = 0; i < 4; ++i) {
                    const int rowA = wrow * 64 + i * 16 + ln15;
                    const int ba = (rowA * 128 + (kk * 32 + hi * 8) * 2) ^ ((rowA & 7) << 4);
                    afr[i] = *(const short8*)((const char*)lsA + ba);
                    const int rowB = wcol * 64 + i * 16 + ln15;
                    const int bb = (rowB * 128 + (kk * 32 + hi * 8) * 2) ^ ((rowB & 7) << 4);
                    bfr[i] = *(const short8*)((const char*)lsB + bb);
                }
#pragma unroll
                for (int i = 0; i < 4; ++i)
#pragma unroll
                    for (int j = 0; j < 4; ++j)
                        acc[i][j] = __builtin_amdgcn_mfma_f32_16x16x32_bf16(afr[i], bfr[j], acc[i][j], 0, 0, 0);
            }
        }

#pragma unroll
        for (int i = 0; i < 4; ++i)
#pragma unroll
            for (int j = 0; j < 4; ++j) {
                const int m = chunk * 128 + wcol * 64 + j * 16 + ln15;
                const float c = c_lds[m];
#pragma unroll
                for (int r = 0; r < 4; ++r) {
                    const float d = acc[i][j][r] - c;
                    p[i * 4 + r] += d * d;
                }
            }
    }

#pragma unroll
    for (int q = 0; q < 16; ++q) {
        float v = p[q];
        v += __shfl_xor(v, 1);
        v += __shfl_xor(v, 2);
        v += __shfl_xor(v, 4);
        v += __shfl_xor(v, 8);
        p[q] = v;
    }
    __syncthreads();
    if (ln15 == 0) {
#pragma unroll
        for (int i = 0; i < 4; ++i)
#pragma unroll
            for (int r = 0; r < 4; ++r)
                red[wcol][wrow * 64 + i * 16 + hi * 4 + r] = p[i * 4 + r];
    }
    __syncthreads();
    if (t < 128) {
        const float sq = (red[0][t] + red[1][t]) * (1.0f / 512.0f);
        const float lc = -50.0f * sq;
        const size_t b = (size_t)tile * 128 + t;
        out[b * NCLS + n] = expf(lc);
        out[(size_t)NBATCH * NCLS + b * NCLS + n] = lc;
    }
}

extern "C" void kernel_launch(void* const* d_in, const int* in_sizes, int n_in,
                              void* d_out, int out_size, void* d_ws, size_t ws_size,
                              hipStream_t stream) {
    const float* x    = (const float*)d_in[0];
    const float* w    = (const float*)d_in[1];
    const float* csum = (const float*)d_in[2];
    const float* cnum = (const float*)d_in[3];
    float* out = (float*)d_out;

    const size_t need = ((size_t)NBATCH * FDIM + (size_t)CDIM * NCLS * FDIM) * sizeof(unsigned short);

    if (ws_size >= need) {
        unsigned short* xb = (unsigned short*)d_ws;
        unsigned short* wb = xb + (size_t)NBATCH * FDIM;
        cvt_x_kernel<<<dim3((NBATCH * FDIM) / 2048), dim3(256), 0, stream>>>(x, xb);
        cvt_w_kernel<<<dim3(CDIM * NCLS), dim3(128), 0, stream>>>(w, wb);
        duq8<<<dim3(NCLS * 16), dim3(512), 0, stream>>>(xb, wb, csum, cnum, out);
    } else {
        duq_fallback<<<dim3(NCLS * 32), dim3(256), 0, stream>>>(x, w, csum, cnum, out);
    }
}